// Round 4
// baseline (265.858 us; speedup 1.0000x reference)
//
#include <hip/hip_runtime.h>
#include <math.h>

#define CPB 4                       // chunks of 256 rows per block
#define ROWS_PER_BLOCK (256 * CPB)  // 1024

// Fast softplus via HW v_exp_f32/v_log_f32 (threshold 0.117 — ample).
__device__ __forceinline__ float fast_softplus(float x) {
    return fmaxf(x, 0.0f) + __logf(1.0f + __expf(-fabsf(x)));
}

struct Row {
    float  xb, yb;
    int    lab;
    float4 xt, yt;
    float4 r0, r1, r2, r3;   // 16 source logits
};

__device__ __forceinline__ Row load_row(const float* __restrict__ pb,
                                        const float* __restrict__ tb,
                                        const int*   __restrict__ ts,
                                        const float4* __restrict__ pt4,
                                        const float4* __restrict__ tt4,
                                        const float4* __restrict__ ps4,
                                        int row)
{
    Row R;
    R.xb  = pb[row];
    R.yb  = tb[row];
    R.lab = ts[row];
    R.xt  = pt4[row];
    R.yt  = tt4[row];
    size_t b = (size_t)row * 4;
    R.r0 = ps4[b + 0];
    R.r1 = ps4[b + 1];
    R.r2 = ps4[b + 2];
    R.r3 = ps4[b + 3];
    return R;
}

__device__ __forceinline__ float row_contrib(const Row& R)
{
    // binary BCE: softplus(x) - y*x
    float c = fast_softplus(R.xb) - R.yb * R.xb;
    bool bin_c = (R.xb >= 0.0f);

    // type BCE (mean of 4) + any(sigmoid>=0.5)
    float tsum = (fast_softplus(R.xt.x) - R.yt.x * R.xt.x)
               + (fast_softplus(R.xt.y) - R.yt.y * R.xt.y)
               + (fast_softplus(R.xt.z) - R.yt.z * R.xt.z)
               + (fast_softplus(R.xt.w) - R.yt.w * R.xt.w);
    c += 0.25f * tsum;
    bool type_c = (R.xt.x >= 0.0f) || (R.xt.y >= 0.0f) ||
                  (R.xt.z >= 0.0f) || (R.xt.w >= 0.0f);

    // 16-class CE: lse(v) - v[lab]
    float v[16] = { R.r0.x, R.r0.y, R.r0.z, R.r0.w,
                    R.r1.x, R.r1.y, R.r1.z, R.r1.w,
                    R.r2.x, R.r2.y, R.r2.z, R.r2.w,
                    R.r3.x, R.r3.y, R.r3.z, R.r3.w };
    float m = v[0];
    #pragma unroll
    for (int j = 1; j < 16; ++j) m = fmaxf(m, v[j]);
    float s = 0.0f;
    #pragma unroll
    for (int j = 0; j < 16; ++j) s += __expf(v[j] - m);
    float vlab = v[0];
    #pragma unroll
    for (int j = 1; j < 16; ++j) vlab = (R.lab == j) ? v[j] : vlab;
    c += m + __logf(s) - vlab;

    // argmax(v) > 0  <=>  max(v[1:]) > v[0]  (first-max tie-break)
    float mr = v[1];
    #pragma unroll
    for (int j = 2; j < 16; ++j) mr = fmaxf(mr, v[j]);
    bool src_c = (mr > v[0]);

    c += (bin_c != type_c) ? 1.0f : 0.0f;
    c += (bin_c != src_c)  ? 1.0f : 0.0f;
    return c;
}

// Persistent per-block loop over CPB chunks, register prefetch distance 1,
// NO barriers in the hot path (no vmcnt(0) convoys). launch_bounds(256,2)
// lifts the VGPR ceiling to 256 so loads stay in flight.
__global__ __launch_bounds__(256, 2) void multitask_loss_kernel(
    const float*  __restrict__ pb,
    const float4* __restrict__ pt4,
    const float4* __restrict__ ps4,
    const float*  __restrict__ tb,
    const float4* __restrict__ tt4,
    const int*    __restrict__ ts,
    float*        __restrict__ partials)
{
    const int tid = threadIdx.x;
    const int row0 = blockIdx.x * ROWS_PER_BLOCK + tid;

    float acc = 0.0f;
    Row cur = load_row(pb, tb, ts, pt4, tt4, ps4, row0);
    #pragma unroll
    for (int i = 0; i < CPB - 1; ++i) {
        Row nxt = load_row(pb, tb, ts, pt4, tt4, ps4, row0 + (i + 1) * 256);
        acc += row_contrib(cur);
        cur = nxt;
    }
    acc += row_contrib(cur);

    // wave-64 reduce -> block partial
    #pragma unroll
    for (int off = 32; off > 0; off >>= 1)
        acc += __shfl_down(acc, off, 64);

    __shared__ float wsum[4];
    const int lane = tid & 63;
    const int wave = tid >> 6;
    if (lane == 0) wsum[wave] = acc;
    __syncthreads();
    if (tid == 0)
        partials[blockIdx.x] = wsum[0] + wsum[1] + wsum[2] + wsum[3];
}

// Final reduce; also handles the (normally empty) tail rows [n_main, B).
__global__ __launch_bounds__(256) void reduce_kernel(
    const float* __restrict__ partials, int nblocks,
    const float*  __restrict__ pb,
    const float4* __restrict__ pt4,
    const float4* __restrict__ ps4,
    const float*  __restrict__ tb,
    const float4* __restrict__ tt4,
    const int*    __restrict__ ts,
    int n_main, int B,
    float* __restrict__ out, double invB)
{
    double s = 0.0;
    for (int i = threadIdx.x; i < nblocks; i += 256)
        s += (double)partials[i];
    for (int r = n_main + threadIdx.x; r < B; r += 256)
        s += (double)row_contrib(load_row(pb, tb, ts, pt4, tt4, ps4, r));

    #pragma unroll
    for (int off = 32; off > 0; off >>= 1)
        s += __shfl_down(s, off, 64);

    __shared__ double wsum[4];
    int lane = threadIdx.x & 63;
    int wave = threadIdx.x >> 6;
    if (lane == 0) wsum[wave] = s;
    __syncthreads();
    if (threadIdx.x == 0)
        out[0] = (float)((wsum[0] + wsum[1] + wsum[2] + wsum[3]) * invB);
}

extern "C" void kernel_launch(void* const* d_in, const int* in_sizes, int n_in,
                              void* d_out, int out_size, void* d_ws, size_t ws_size,
                              hipStream_t stream) {
    const float*  pb  = (const float*)d_in[0];
    const float4* pt4 = (const float4*)d_in[1];
    const float4* ps4 = (const float4*)d_in[2];
    const float*  tb  = (const float*)d_in[3];
    const float4* tt4 = (const float4*)d_in[4];
    const int*    ts  = (const int*)d_in[5];
    int B = in_sizes[0];                      // 2097152 = 2048 * 1024

    float* partials = (float*)d_ws;           // [grid] fully overwritten

    int grid   = B / ROWS_PER_BLOCK;          // 2048 full blocks
    int n_main = grid * ROWS_PER_BLOCK;       // tail handled in reduce_kernel

    multitask_loss_kernel<<<grid, 256, 0, stream>>>(pb, pt4, ps4, tb, tt4, ts,
                                                    partials);
    reduce_kernel<<<1, 256, 0, stream>>>(partials, grid,
                                         pb, pt4, ps4, tb, tt4, ts,
                                         n_main, B, (float*)d_out,
                                         1.0 / (double)B);
}